// Round 6
// baseline (3029.650 us; speedup 1.0000x reference)
//
#include <hip/hip_runtime.h>

typedef __attribute__((ext_vector_type(4))) float f32x4;
typedef __attribute__((ext_vector_type(8))) short bf16x8;

#define B_   128
#define T_   1024
#define NROW 131072      // B*T
#define HB   (NROW*300)  // floats in the [B*T][300] matrix

__device__ inline unsigned short f2bf(float f) {
    union { float f; unsigned int u; } v; v.f = f;
    unsigned int r = v.u + 0x7FFFu + ((v.u >> 16) & 1u);
    return (unsigned short)(r >> 16);
}

// Load up to 8 consecutive f32 (zero-masked at K=300 boundary), convert to bf16,
// return packed uint4 (8 bf16, fragment j-order = ascending k).
__device__ inline uint4 load8_cvt(const float* src, bool rowok, int krem) {
    f32x4 v0 = {0.f,0.f,0.f,0.f}, v1 = {0.f,0.f,0.f,0.f};
    if (rowok) {
        if (krem >= 8)      { v0 = *(const f32x4*)src; v1 = *(const f32x4*)(src + 4); }
        else if (krem >= 4) { v0 = *(const f32x4*)src; }
    }
    uint4 p;
    p.x = (unsigned)f2bf(v0[0]) | ((unsigned)f2bf(v0[1]) << 16);
    p.y = (unsigned)f2bf(v0[2]) | ((unsigned)f2bf(v0[3]) << 16);
    p.z = (unsigned)f2bf(v1[0]) | ((unsigned)f2bf(v1[1]) << 16);
    p.w = (unsigned)f2bf(v1[2]) | ((unsigned)f2bf(v1[3]) << 16);
    return p;
}

// ---------------------------------------------------------------------------
// K1: A[m][n] = sum_k X[m][k]*W1[n][k] + b1[n]   (bf16 MFMA, f32 out)
// ---------------------------------------------------------------------------
__global__ __launch_bounds__(256) void gemm_in(
    const float* __restrict__ X, const float* __restrict__ W1,
    const float* __restrict__ b1, float* __restrict__ A)
{
    __shared__ unsigned short alds[8 * 64 * 8];
    __shared__ unsigned short blds[10 * 64 * 8];
    const int tid = threadIdx.x;
    const int w = tid >> 6, l = tid & 63, lg = l >> 4, ln = l & 15;
    const size_t m0 = (size_t)blockIdx.x * 128;
    const int n0 = blockIdx.y * 160;

    f32x4 acc[2][10];
    #pragma unroll
    for (int q = 0; q < 2; ++q)
        #pragma unroll
        for (int nt = 0; nt < 10; ++nt) acc[q][nt] = (f32x4){0.f,0.f,0.f,0.f};

    for (int kt = 0; kt < 10; ++kt) {
        const int kc = kt * 32;
        __syncthreads();
        #pragma unroll
        for (int rep = 0; rep < 2; ++rep) {
            int e = tid + rep * 256;
            int row = e >> 2, kh = e & 3;
            int k0 = kc + kh * 8;
            uint4 p = load8_cvt(X + (m0 + row) * 300 + k0, true, 300 - k0);
            *(uint4*)&alds[(((row >> 4) * 64) + kh * 16 + (row & 15)) * 8] = p;
        }
        #pragma unroll
        for (int rep = 0; rep < 3; ++rep) {
            int e = tid + rep * 256;
            if (e < 640) {
                int nn = e >> 2, kh = e & 3;
                int n = n0 + nn;
                int k0 = kc + kh * 8;
                uint4 p = load8_cvt(W1 + (size_t)n * 600 + k0, n < 300, 300 - k0);
                *(uint4*)&blds[(((nn >> 4) * 64) + kh * 16 + (nn & 15)) * 8] = p;
            }
        }
        __syncthreads();
        bf16x8 bfr[10];
        #pragma unroll
        for (int nt = 0; nt < 10; ++nt) bfr[nt] = *(const bf16x8*)&blds[(nt * 64 + l) * 8];
        #pragma unroll
        for (int q = 0; q < 2; ++q) {
            bf16x8 afr = *(const bf16x8*)&alds[((w * 2 + q) * 64 + l) * 8];
            #pragma unroll
            for (int nt = 0; nt < 10; ++nt)
                acc[q][nt] = __builtin_amdgcn_mfma_f32_16x16x32_bf16(afr, bfr[nt], acc[q][nt], 0, 0, 0);
        }
    }

    #pragma unroll
    for (int q = 0; q < 2; ++q)
        #pragma unroll
        for (int nt = 0; nt < 10; ++nt) {
            int n = n0 + nt * 16 + ln;
            if (n < 300) {
                float bias = b1[n];
                size_t mr = m0 + (w * 2 + q) * 16 + lg * 4;
                #pragma unroll
                for (int i = 0; i < 4; ++i)
                    A[(mr + i) * 300 + n] = acc[q][nt][i] + bias;
            }
        }
}

// ---------------------------------------------------------------------------
// K2: recurrence. 8 blocks x 512 thr. All global traffic COALESCED:
//  - A(t+2) loaded as contiguous 16B units (batch e/75, off e%75) into regs,
//    ds_written next step into padded LDS slot [2][16][308], consumed from LDS.
//  - packed h(t-1) stored by re-reading hlds and writing contiguous 8B units.
// MFMA chains split (kt 0-4 / 5-9). One raw s_barrier + lgkmcnt(0) per step.
// Race-free: stores at step t cover times <= t-1; stage loads read t+2.
// ---------------------------------------------------------------------------
#define QOK(q) ((q) < 2 || w4)
#define UOK(r) ((r) < 2 || u2ok)

#define K2S(P, tval, REGW, REGL)                                                \
    {                                                                           \
        const int t = (tval);                                                   \
        /* cooperative store of packed h(t-1) from hlds[P] */                   \
        if (t > 0) {                                                            \
            const int tt = t - 1;                                               \
            _Pragma("unroll")                                                   \
            for (int r = 0; r < 3; ++r) if (UOK(r)) {                           \
                uint2 hv2 = *(const uint2*)((const char*)&hlds[P][0] + hsrc[r]); \
                char* dst = (char*)buf +                                        \
                    (size_t)((b0 + ub[r]) * 16 + (tt >> 6)) * 76800 +           \
                    (size_t)(tt & 63) * 600 + uv[r] * 8;                        \
                *(uint2*)dst = hv2;                                             \
            }                                                                   \
        }                                                                       \
        /* A(t) values from staged LDS */                                       \
        f32x4 av[3];                                                            \
        _Pragma("unroll")                                                       \
        for (int q = 0; q < 3; ++q)                                             \
            if (QOK(q)) av[q] = *(const f32x4*)&astage[P][aoff[q]];             \
        /* stage-write A(t+1) (loaded last step) into other slot */             \
        _Pragma("unroll")                                                       \
        for (int r = 0; r < 3; ++r)                                             \
            if (UOK(r)) *(uint4*)&astage[(P) ^ 1][swoff[r]] = REGW[r];          \
        /* B-frags + split MFMA chains */                                       \
        bf16x8 bfr[10];                                                         \
        _Pragma("unroll")                                                       \
        for (int kt = 0; kt < 10; ++kt)                                         \
            bfr[kt] = *(const bf16x8*)&hlds[P][(kt * 64 + l) * 8];              \
        f32x4 acc[3], accB[3];                                                  \
        _Pragma("unroll")                                                       \
        for (int q = 0; q < 3; ++q) { acc[q] = (f32x4){0.f,0.f,0.f,0.f}; accB[q] = acc[q]; } \
        _Pragma("unroll")                                                       \
        for (int kt = 0; kt < 5; ++kt) {                                        \
            acc[0]  = __builtin_amdgcn_mfma_f32_16x16x32_bf16(afrag[0][kt],   bfr[kt],   acc[0],  0, 0, 0); \
            accB[0] = __builtin_amdgcn_mfma_f32_16x16x32_bf16(afrag[0][kt+5], bfr[kt+5], accB[0], 0, 0, 0); \
            acc[1]  = __builtin_amdgcn_mfma_f32_16x16x32_bf16(afrag[1][kt],   bfr[kt],   acc[1],  0, 0, 0); \
            accB[1] = __builtin_amdgcn_mfma_f32_16x16x32_bf16(afrag[1][kt+5], bfr[kt+5], accB[1], 0, 0, 0); \
            if (w4) {                                                           \
                acc[2]  = __builtin_amdgcn_mfma_f32_16x16x32_bf16(afrag[2][kt],   bfr[kt],   acc[2],  0, 0, 0); \
                accB[2] = __builtin_amdgcn_mfma_f32_16x16x32_bf16(afrag[2][kt+5], bfr[kt+5], accB[2], 0, 0, 0); \
            }                                                                   \
        }                                                                       \
        /* sigmoid + pack + hlds write + hfinal */                              \
        _Pragma("unroll")                                                       \
        for (int q = 0; q < 3; ++q) {                                           \
            if (!QOK(q)) continue;                                              \
            f32x4 hv;                                                           \
            _Pragma("unroll")                                                   \
            for (int i = 0; i < 4; ++i) {                                       \
                float z = acc[q][i] + accB[q][i] + av[q][i];                    \
                hv[i] = 1.f / (1.f + __expf(-z));                               \
            }                                                                   \
            unsigned plo, phi;                                                  \
            asm("v_cvt_pk_bf16_f32 %0, %1, %2" : "=v"(plo) : "v"(hv[0]), "v"(hv[1])); \
            asm("v_cvt_pk_bf16_f32 %0, %1, %2" : "=v"(phi) : "v"(hv[2]), "v"(hv[3])); \
            uint2 pk; pk.x = plo; pk.y = phi;                                   \
            *(uint2*)((char*)hlds + ((P) ^ 1) * 10240 + ldsoff[q]) = pk;        \
            if (t == T_ - 1 && rq[q] < 300)                                     \
                *(f32x4*)(hfinal + bb * 300 + rq[q]) = hv;                      \
        }                                                                       \
        /* coalesced stage-load A(t+2) -> REGL */                               \
        {                                                                       \
            const int tpf = (t + 2 < T_) ? (t + 2) : (T_ - 1);                  \
            _Pragma("unroll")                                                   \
            for (int r = 0; r < 3; ++r)                                         \
                if (UOK(r))                                                     \
                    REGL[r] = *(const uint4*)(buf + ((size_t)(b0 + ub[r]) * T_ + tpf) * 300 + uv[r] * 4); \
        }                                                                       \
        asm volatile("s_waitcnt lgkmcnt(0)" ::: "memory");                      \
        __builtin_amdgcn_s_barrier();                                           \
        asm volatile("" ::: "memory");                                          \
    }

__global__ __launch_bounds__(512) void elman_rec_mfma(
    const float* __restrict__ W1, float* __restrict__ buf,
    float* __restrict__ hfinal)
{
    __shared__ unsigned short hlds[2][10 * 64 * 8];   // 2 x 10240 B
    __shared__ float astage[2][16 * 308];             // 2 x 19712 B (padded rows)
    const int tid = threadIdx.x;
    const int w = tid >> 6, l = tid & 63, lg = l >> 4, ln = l & 15;
    const bool w4 = (w < 4);
    const int b0 = blockIdx.x * 16;
    const int bb = b0 + ln;

    // cooperative-unit constants: unit e = r*512+tid -> batch e/75, 16B-off e%75
    int ub[3], uv[3], hsrc[3], swoff[3];
    #pragma unroll
    for (int r = 0; r < 3; ++r) {
        int e = r * 512 + tid;
        ub[r] = e / 75; uv[r] = e - ub[r] * 75;
        int v = uv[r]; int kt = v >> 3, g = (v >> 1) & 3;
        hsrc[r]  = (((kt * 64 + g * 16 + ub[r]) * 8) + (v & 1) * 4) * 2;  // bytes in hlds[P]
        swoff[r] = ub[r] * 308 + uv[r] * 4;                               // floats in astage slot
    }
    const bool u2ok = (tid < 176);

    int rq[3], ldsoff[3], aoff[3];
    #pragma unroll
    for (int q = 0; q < 3; ++q) {
        int tile = w4 ? (3 * w + q) : (12 + 2 * (w - 4) + q);
        int r = tile * 16 + 4 * lg;
        rq[q] = r;
        ldsoff[q] = (((r >> 5) * 64 + ((r >> 3) & 3) * 16 + ln) * 8 + (r & 7)) * 2;
        aoff[q] = ln * 308 + ((r < 300) ? r : 296);
    }

    // W1h A-fragments into registers (rows >=300, k>=300 zeroed)
    bf16x8 afrag[3][10];
    #pragma unroll
    for (int q = 0; q < 3; ++q) {
        #pragma unroll
        for (int kt = 0; kt < 10; ++kt) {
            bool qa = (q < 2) || w4;
            int tile = w4 ? (3 * w + q) : (12 + 2 * (w - 4) + q);
            int r = tile * 16 + ln;
            int k0 = kt * 32 + lg * 8;
            uint4 p = load8_cvt(W1 + (size_t)r * 600 + 300 + k0,
                                qa && r < 300, 300 - k0);
            union { uint4 u; bf16x8 s; } cv; cv.u = p;
            afrag[q][kt] = cv.s;
        }
    }

    for (int i = tid; i < 10 * 64 * 8; i += 512) hlds[0][i] = 0;

    // prologue: stage A(0) directly into slot 0; issue loads A(1) -> regs1
    uint4 regs0[3], regs1[3];
    #pragma unroll
    for (int r = 0; r < 3; ++r) if (UOK(r)) {
        uint4 d = *(const uint4*)(buf + (size_t)(b0 + ub[r]) * T_ * 300 + uv[r] * 4);
        *(uint4*)&astage[0][swoff[r]] = d;
        regs1[r] = *(const uint4*)(buf + ((size_t)(b0 + ub[r]) * T_ + 1) * 300 + uv[r] * 4);
    }
    __syncthreads();

    for (int t2 = 0; t2 < T_; t2 += 2) {
        K2S(0, t2,     regs1, regs0)
        K2S(1, t2 + 1, regs0, regs1)
    }

    // tail: cooperative store of packed h(1023) (lives in hlds[0])
    {
        const int tt = T_ - 1;
        #pragma unroll
        for (int r = 0; r < 3; ++r) if (UOK(r)) {
            uint2 hv2 = *(const uint2*)((const char*)&hlds[0][0] + hsrc[r]);
            char* dst = (char*)buf +
                (size_t)((b0 + ub[r]) * 16 + (tt >> 6)) * 76800 +
                (size_t)(tt & 63) * 600 + uv[r] * 8;
            *(uint2*)dst = hv2;
        }
    }
}

// ---------------------------------------------------------------------------
// K3: out[m][n] = sum_k h[m][k]*W2[n][k] + b2[n], in place over packed-h buf.
// One block per 64-row chunk (grid 2048); block computes ALL 300 columns.
// ---------------------------------------------------------------------------
__global__ __launch_bounds__(256) void gemm_out(
    float* __restrict__ buf, const float* __restrict__ W2,
    const float* __restrict__ b2)
{
    __shared__ unsigned short alds[4 * 64 * 8];
    __shared__ unsigned short blds[19 * 64 * 8];
    const int tid = threadIdx.x;
    const int w = tid >> 6, l = tid & 63, lg = l >> 4, ln = l & 15;
    const size_t chunk = blockIdx.x;
    const char* pbase = (const char*)buf + chunk * 76800;

    f32x4 acc[19];
    #pragma unroll
    for (int nt = 0; nt < 19; ++nt) acc[nt] = (f32x4){0.f,0.f,0.f,0.f};

    for (int kt = 0; kt < 10; ++kt) {
        const int kc = kt * 32;
        __syncthreads();
        {
            int row = tid >> 2, kh = tid & 3;
            int k0 = kc + kh * 8;
            const char* p = pbase + row * 600;
            uint2 lo = make_uint2(0u, 0u), hi = make_uint2(0u, 0u);
            int krem = 300 - k0;
            if (krem >= 8)      { lo = *(const uint2*)(p + k0 * 2); hi = *(const uint2*)(p + k0 * 2 + 8); }
            else if (krem >= 4) { lo = *(const uint2*)(p + k0 * 2); }
            uint4 pk; pk.x = lo.x; pk.y = lo.y; pk.z = hi.x; pk.w = hi.y;
            *(uint4*)&alds[(((row >> 4) * 64) + kh * 16 + (row & 15)) * 8] = pk;
        }
        #pragma unroll
        for (int rep = 0; rep < 5; ++rep) {
            int e = tid + rep * 256;
            if (e < 1216) {
                int nn = e >> 2, kh = e & 3;
                int k0 = kc + kh * 8;
                uint4 p = load8_cvt(W2 + (size_t)nn * 300 + k0, nn < 300, 300 - k0);
                *(uint4*)&blds[(((nn >> 4) * 64) + kh * 16 + (nn & 15)) * 8] = p;
            }
        }
        __syncthreads();
        bf16x8 afr = *(const bf16x8*)&alds[(w * 64 + l) * 8];
        #pragma unroll
        for (int nt = 0; nt < 19; ++nt) {
            bf16x8 bfr = *(const bf16x8*)&blds[(nt * 64 + l) * 8];
            acc[nt] = __builtin_amdgcn_mfma_f32_16x16x32_bf16(afr, bfr, acc[nt], 0, 0, 0);
        }
    }

    float* frow = buf + chunk * 19200;
    #pragma unroll
    for (int nt = 0; nt < 19; ++nt) {
        int n = nt * 16 + ln;
        if (n < 300) {
            float bias = b2[n];
            int mr = w * 16 + lg * 4;
            #pragma unroll
            for (int i = 0; i < 4; ++i)
                frow[(mr + i) * 300 + n] = acc[nt][i] + bias;
        }
    }
}

// ---------------------------------------------------------------------------
extern "C" void kernel_launch(void* const* d_in, const int* in_sizes, int n_in,
                              void* d_out, int out_size, void* d_ws, size_t ws_size,
                              hipStream_t stream)
{
    const float* x  = (const float*)d_in[0];
    const float* W1 = (const float*)d_in[1];
    const float* b1 = (const float*)d_in[2];
    const float* W2 = (const float*)d_in[3];
    const float* b2 = (const float*)d_in[4];

    float* out    = (float*)d_out;
    float* hfinal = out + (size_t)HB;

    gemm_in<<<dim3(1024, 2), 256, 0, stream>>>(x, W1, b1, out);
    elman_rec_mfma<<<8, 512, 0, stream>>>(W1, out, hfinal);
    gemm_out<<<2048, 256, 0, stream>>>(out, W2, b2);
}

// Round 7
// 1878.590 us; speedup vs baseline: 1.6127x; 1.6127x over previous
//
#include <hip/hip_runtime.h>

typedef __attribute__((ext_vector_type(4))) float f32x4;
typedef __attribute__((ext_vector_type(8))) short bf16x8;

#define B_   128
#define T_   1024
#define NROW 131072      // B*T
#define HB   (NROW*300)  // floats in the [B*T][300] matrix
#define NL2E -1.44269504088896340736f   // -log2(e)

__device__ inline unsigned short f2bf(float f) {
    union { float f; unsigned int u; } v; v.f = f;
    unsigned int r = v.u + 0x7FFFu + ((v.u >> 16) & 1u);
    return (unsigned short)(r >> 16);
}

// Load up to 8 consecutive f32 (zero-masked at K=300 boundary), scale, convert
// to bf16, return packed uint4 (8 bf16, fragment j-order = ascending k).
__device__ inline uint4 load8_cvt_s(const float* src, bool rowok, int krem, float scale) {
    f32x4 v0 = {0.f,0.f,0.f,0.f}, v1 = {0.f,0.f,0.f,0.f};
    if (rowok) {
        if (krem >= 8)      { v0 = *(const f32x4*)src; v1 = *(const f32x4*)(src + 4); }
        else if (krem >= 4) { v0 = *(const f32x4*)src; }
    }
    v0 *= scale; v1 *= scale;
    uint4 p;
    p.x = (unsigned)f2bf(v0[0]) | ((unsigned)f2bf(v0[1]) << 16);
    p.y = (unsigned)f2bf(v0[2]) | ((unsigned)f2bf(v0[3]) << 16);
    p.z = (unsigned)f2bf(v1[0]) | ((unsigned)f2bf(v1[1]) << 16);
    p.w = (unsigned)f2bf(v1[2]) | ((unsigned)f2bf(v1[3]) << 16);
    return p;
}

__device__ inline uint4 load8_cvt(const float* src, bool rowok, int krem) {
    return load8_cvt_s(src, rowok, krem, 1.0f);
}

// ---------------------------------------------------------------------------
// K1: A[m][n] = -log2e * (sum_k X[m][k]*W1[n][k] + b1[n])   (bf16 MFMA)
// The -log2e pre-scale lets K2's sigmoid use raw v_exp_f32 (2^x) directly.
// ---------------------------------------------------------------------------
__global__ __launch_bounds__(256) void gemm_in(
    const float* __restrict__ X, const float* __restrict__ W1,
    const float* __restrict__ b1, float* __restrict__ A)
{
    __shared__ unsigned short alds[8 * 64 * 8];
    __shared__ unsigned short blds[10 * 64 * 8];
    const int tid = threadIdx.x;
    const int w = tid >> 6, l = tid & 63, lg = l >> 4, ln = l & 15;
    const size_t m0 = (size_t)blockIdx.x * 128;
    const int n0 = blockIdx.y * 160;

    f32x4 acc[2][10];
    #pragma unroll
    for (int q = 0; q < 2; ++q)
        #pragma unroll
        for (int nt = 0; nt < 10; ++nt) acc[q][nt] = (f32x4){0.f,0.f,0.f,0.f};

    for (int kt = 0; kt < 10; ++kt) {
        const int kc = kt * 32;
        __syncthreads();
        #pragma unroll
        for (int rep = 0; rep < 2; ++rep) {
            int e = tid + rep * 256;
            int row = e >> 2, kh = e & 3;
            int k0 = kc + kh * 8;
            uint4 p = load8_cvt(X + (m0 + row) * 300 + k0, true, 300 - k0);
            *(uint4*)&alds[(((row >> 4) * 64) + kh * 16 + (row & 15)) * 8] = p;
        }
        #pragma unroll
        for (int rep = 0; rep < 3; ++rep) {
            int e = tid + rep * 256;
            if (e < 640) {
                int nn = e >> 2, kh = e & 3;
                int n = n0 + nn;
                int k0 = kc + kh * 8;
                uint4 p = load8_cvt(W1 + (size_t)n * 600 + k0, n < 300, 300 - k0);
                *(uint4*)&blds[(((nn >> 4) * 64) + kh * 16 + (nn & 15)) * 8] = p;
            }
        }
        __syncthreads();
        bf16x8 bfr[10];
        #pragma unroll
        for (int nt = 0; nt < 10; ++nt) bfr[nt] = *(const bf16x8*)&blds[(nt * 64 + l) * 8];
        #pragma unroll
        for (int q = 0; q < 2; ++q) {
            bf16x8 afr = *(const bf16x8*)&alds[((w * 2 + q) * 64 + l) * 8];
            #pragma unroll
            for (int nt = 0; nt < 10; ++nt)
                acc[q][nt] = __builtin_amdgcn_mfma_f32_16x16x32_bf16(afr, bfr[nt], acc[q][nt], 0, 0, 0);
        }
    }

    #pragma unroll
    for (int q = 0; q < 2; ++q)
        #pragma unroll
        for (int nt = 0; nt < 10; ++nt) {
            int n = n0 + nt * 16 + ln;
            if (n < 300) {
                float bias = b1[n];
                size_t mr = m0 + (w * 2 + q) * 16 + lg * 4;
                #pragma unroll
                for (int i = 0; i < 4; ++i)
                    A[(mr + i) * 300 + n] = (acc[q][nt][i] + bias) * NL2E;
            }
        }
}

// ---------------------------------------------------------------------------
// K2: recurrence. 8 blocks x 512 thr (8 waves). W1h (bf16, -log2e-scaled) in
// VGPR/AGPR A-frags; h via double-buffered LDS B-frags; one raw s_barrier +
// lgkmcnt(0) per step (globals stay in flight). A' (=-log2e*z_pre) folded in
// as MFMA C-init. Sigmoid = v_exp_f32 + add + v_rcp_f32 (no IEEE div).
// Race-free delayed-store scheme: stores at step t cover times <= t-1;
// prefetch reads t+2; per-lane same-address pairs never overlap in time.
// ---------------------------------------------------------------------------
#define QOK(q) ((q) < 2 || w4)

#define K2_STEP(P, tval, ASLOT, HPME, HPOTHER)                                  \
    {                                                                           \
        const int t = (tval);                                                   \
        if (t > 0) {                                                            \
            const int tt = t - 1;                                               \
            const size_t so = (size_t)(tt >> 6) * 76800 + (size_t)(tt & 63) * 600; \
            _Pragma("unroll")                                                   \
            for (int q = 0; q < 3; ++q)                                         \
                if (QOK(q) && rq[q] < 300)                                      \
                    *(uint2*)(sbase + so + rq[q] * 2) = HPOTHER[q];             \
        }                                                                       \
        bf16x8 bfr[10];                                                         \
        _Pragma("unroll")                                                       \
        for (int kt = 0; kt < 10; ++kt)                                         \
            bfr[kt] = *(const bf16x8*)&hlds[P][(kt * 64 + l) * 8];              \
        f32x4 acc[3], accB[3];                                                  \
        _Pragma("unroll")                                                       \
        for (int q = 0; q < 3; ++q) {                                           \
            acc[q] = QOK(q) ? ASLOT[q] : (f32x4){0.f,0.f,0.f,0.f};              \
            accB[q] = (f32x4){0.f,0.f,0.f,0.f};                                 \
        }                                                                       \
        _Pragma("unroll")                                                       \
        for (int kt = 0; kt < 5; ++kt) {                                        \
            acc[0]  = __builtin_amdgcn_mfma_f32_16x16x32_bf16(afrag[0][kt],   bfr[kt],   acc[0],  0, 0, 0); \
            accB[0] = __builtin_amdgcn_mfma_f32_16x16x32_bf16(afrag[0][kt+5], bfr[kt+5], accB[0], 0, 0, 0); \
            acc[1]  = __builtin_amdgcn_mfma_f32_16x16x32_bf16(afrag[1][kt],   bfr[kt],   acc[1],  0, 0, 0); \
            accB[1] = __builtin_amdgcn_mfma_f32_16x16x32_bf16(afrag[1][kt+5], bfr[kt+5], accB[1], 0, 0, 0); \
            if (w4) {                                                           \
                acc[2]  = __builtin_amdgcn_mfma_f32_16x16x32_bf16(afrag[2][kt],   bfr[kt],   acc[2],  0, 0, 0); \
                accB[2] = __builtin_amdgcn_mfma_f32_16x16x32_bf16(afrag[2][kt+5], bfr[kt+5], accB[2], 0, 0, 0); \
            }                                                                   \
        }                                                                       \
        _Pragma("unroll")                                                       \
        for (int q = 0; q < 3; ++q) {                                           \
            if (!QOK(q)) continue;                                              \
            f32x4 hv;                                                           \
            _Pragma("unroll")                                                   \
            for (int i = 0; i < 4; ++i) {                                       \
                float zn = acc[q][i] + accB[q][i];      /* = -z*log2e */        \
                float ex, sg;                                                   \
                asm("v_exp_f32 %0, %1" : "=v"(ex) : "v"(zn));                   \
                asm("v_rcp_f32 %0, %1" : "=v"(sg) : "v"(1.0f + ex));            \
                hv[i] = sg;                                                     \
            }                                                                   \
            unsigned plo, phi;                                                  \
            asm("v_cvt_pk_bf16_f32 %0, %1, %2" : "=v"(plo) : "v"(hv[0]), "v"(hv[1])); \
            asm("v_cvt_pk_bf16_f32 %0, %1, %2" : "=v"(phi) : "v"(hv[2]), "v"(hv[3])); \
            HPME[q].x = plo; HPME[q].y = phi;                                   \
            *(uint2*)((char*)hlds + ((P) ^ 1) * 10240 + ldsoff[q]) = HPME[q];   \
            if (t == T_ - 1 && rq[q] < 300)                                     \
                *(f32x4*)(hfinal + bb * 300 + rq[q]) = hv;                      \
        }                                                                       \
        if (t < T_ - 2) {                                                       \
            const char* ar = abase + (size_t)(t + 2) * 1200;                    \
            _Pragma("unroll")                                                   \
            for (int q = 0; q < 3; ++q)                                         \
                if (QOK(q)) ASLOT[q] = *(const f32x4*)(ar + rq[q] * 4);         \
        }                                                                       \
        asm volatile("s_waitcnt lgkmcnt(0)" ::: "memory");                      \
        __builtin_amdgcn_s_barrier();                                           \
        asm volatile("" ::: "memory");                                          \
    }

__global__ __launch_bounds__(512) void elman_rec_mfma(
    const float* __restrict__ W1, float* __restrict__ buf,
    float* __restrict__ hfinal)
{
    __shared__ unsigned short hlds[2][10 * 64 * 8];   // 2 x 10240 B
    const int tid = threadIdx.x;
    const int w = tid >> 6, l = tid & 63, lg = l >> 4, ln = l & 15;
    const bool w4 = (w < 4);
    const int bb = blockIdx.x * 16 + ln;    // this lane's batch (B/C column)

    int rq[3], ldsoff[3];
    #pragma unroll
    for (int q = 0; q < 3; ++q) {
        int tile = w4 ? (3 * w + q) : (12 + 2 * (w - 4) + q);
        int r = tile * 16 + 4 * lg;
        rq[q] = r;
        ldsoff[q] = (((r >> 5) * 64 + ((r >> 3) & 3) * 16 + ln) * 8 + (r & 7)) * 2;
    }

    // W1h A-fragments, scaled by -log2e (rows >=300, k>=300 zeroed)
    bf16x8 afrag[3][10];
    #pragma unroll
    for (int q = 0; q < 3; ++q) {
        #pragma unroll
        for (int kt = 0; kt < 10; ++kt) {
            bool qa = (q < 2) || w4;
            int tile = w4 ? (3 * w + q) : (12 + 2 * (w - 4) + q);
            int r = tile * 16 + ln;
            int k0 = kt * 32 + lg * 8;
            uint4 p = load8_cvt_s(W1 + (size_t)r * 600 + 300 + k0,
                                  qa && r < 300, 300 - k0, NL2E);
            union { uint4 u; bf16x8 s; } cv; cv.u = p;
            afrag[q][kt] = cv.s;
        }
    }

    for (int i = tid; i < 10 * 64 * 8; i += 512) hlds[0][i] = 0;

    // per-lane base pointers
    const char* abase = (const char*)(buf + (size_t)bb * T_ * 300);
    char* sbase = (char*)buf + (size_t)bb * 16 * 76800;

    // prefetch A'(0) -> slot0, A'(1) -> slot1
    f32x4 A0[3], A1[3];
    #pragma unroll
    for (int q = 0; q < 3; ++q)
        if (QOK(q)) {
            A0[q] = *(const f32x4*)(abase + rq[q] * 4);
            A1[q] = *(const f32x4*)(abase + 1200 + rq[q] * 4);
        }
    uint2 hpA[3], hpB[3];
    __syncthreads();

    for (int t2 = 0; t2 < T_; t2 += 2) {
        K2_STEP(0, t2,     A0, hpA, hpB)
        K2_STEP(1, t2 + 1, A1, hpB, hpA)
    }

    // tail: packed store for t=1023 (parity 1 -> hpB)
    {
        const int tt = T_ - 1;
        const size_t so = (size_t)(tt >> 6) * 76800 + (size_t)(tt & 63) * 600;
        #pragma unroll
        for (int q = 0; q < 3; ++q)
            if (QOK(q) && rq[q] < 300)
                *(uint2*)(sbase + so + rq[q] * 2) = hpB[q];
    }
}

// ---------------------------------------------------------------------------
// K3: out[m][n] = sum_k h[m][k]*W2[n][k] + b2[n], in place over packed-h buf.
// One block per 64-row chunk (grid 2048); block computes ALL 300 columns.
// ---------------------------------------------------------------------------
__global__ __launch_bounds__(256) void gemm_out(
    float* __restrict__ buf, const float* __restrict__ W2,
    const float* __restrict__ b2)
{
    __shared__ unsigned short alds[4 * 64 * 8];
    __shared__ unsigned short blds[19 * 64 * 8];
    const int tid = threadIdx.x;
    const int w = tid >> 6, l = tid & 63, lg = l >> 4, ln = l & 15;
    const size_t chunk = blockIdx.x;
    const char* pbase = (const char*)buf + chunk * 76800;

    f32x4 acc[19];
    #pragma unroll
    for (int nt = 0; nt < 19; ++nt) acc[nt] = (f32x4){0.f,0.f,0.f,0.f};

    for (int kt = 0; kt < 10; ++kt) {
        const int kc = kt * 32;
        __syncthreads();
        {
            int row = tid >> 2, kh = tid & 3;
            int k0 = kc + kh * 8;
            const char* p = pbase + row * 600;
            uint2 lo = make_uint2(0u, 0u), hi = make_uint2(0u, 0u);
            int krem = 300 - k0;
            if (krem >= 8)      { lo = *(const uint2*)(p + k0 * 2); hi = *(const uint2*)(p + k0 * 2 + 8); }
            else if (krem >= 4) { lo = *(const uint2*)(p + k0 * 2); }
            uint4 pk; pk.x = lo.x; pk.y = lo.y; pk.z = hi.x; pk.w = hi.y;
            *(uint4*)&alds[(((row >> 4) * 64) + kh * 16 + (row & 15)) * 8] = pk;
        }
        #pragma unroll
        for (int rep = 0; rep < 5; ++rep) {
            int e = tid + rep * 256;
            if (e < 1216) {
                int nn = e >> 2, kh = e & 3;
                int k0 = kc + kh * 8;
                uint4 p = load8_cvt(W2 + (size_t)nn * 300 + k0, nn < 300, 300 - k0);
                *(uint4*)&blds[(((nn >> 4) * 64) + kh * 16 + (nn & 15)) * 8] = p;
            }
        }
        __syncthreads();
        bf16x8 afr = *(const bf16x8*)&alds[(w * 64 + l) * 8];
        #pragma unroll
        for (int nt = 0; nt < 19; ++nt) {
            bf16x8 bfr = *(const bf16x8*)&blds[(nt * 64 + l) * 8];
            acc[nt] = __builtin_amdgcn_mfma_f32_16x16x32_bf16(afr, bfr, acc[nt], 0, 0, 0);
        }
    }

    float* frow = buf + chunk * 19200;
    #pragma unroll
    for (int nt = 0; nt < 19; ++nt) {
        int n = nt * 16 + ln;
        if (n < 300) {
            float bias = b2[n];
            int mr = w * 16 + lg * 4;
            #pragma unroll
            for (int i = 0; i < 4; ++i)
                frow[(mr + i) * 300 + n] = acc[nt][i] + bias;
        }
    }
}

// ---------------------------------------------------------------------------
extern "C" void kernel_launch(void* const* d_in, const int* in_sizes, int n_in,
                              void* d_out, int out_size, void* d_ws, size_t ws_size,
                              hipStream_t stream)
{
    const float* x  = (const float*)d_in[0];
    const float* W1 = (const float*)d_in[1];
    const float* b1 = (const float*)d_in[2];
    const float* W2 = (const float*)d_in[3];
    const float* b2 = (const float*)d_in[4];

    float* out    = (float*)d_out;
    float* hfinal = out + (size_t)HB;

    gemm_in<<<dim3(1024, 2), 256, 0, stream>>>(x, W1, b1, out);
    elman_rec_mfma<<<8, 512, 0, stream>>>(W1, out, hfinal);
    gemm_out<<<2048, 256, 0, stream>>>(out, W2, b2);
}